// Round 6
// baseline (707.838 us; speedup 1.0000x reference)
//
#include <hip/hip_runtime.h>
#include <math.h>

#define HW 4096
#define FIXUP_THR 4e-3f

typedef _Float16 half8_t __attribute__((ext_vector_type(8)));
typedef _Float16 half4_t __attribute__((ext_vector_type(4)));
typedef float f32x4 __attribute__((ext_vector_type(4)));

// ------- merged per-batch transpose to fp16 + per-position sumsq partials -------
// one dispatch covers all 4 tensors of batch b: blk [0,1024)=t3, [1024,2048)=s3,
// [2048,4096)=t4, [4096,6144)=s4. f[b][c][pos] -> out[pos][c]; part = per-cblk sumsq.
__global__ __launch_bounds__(256) void transpose_b(
    const float* __restrict__ s3f, const float* __restrict__ t3f,
    const float* __restrict__ s4f, const float* __restrict__ t4f,
    _Float16* __restrict__ P, float* __restrict__ part, int b) {
    __shared__ float tile[64][65];
    const int t = threadIdx.x;
    int blk = blockIdx.x;
    const float* f;
    _Float16* out;
    float* pt;
    int C;
    if (blk < 2048) {
        C = 1024;
        if (blk < 1024) { f = t3f; out = P;            pt = part;          }
        else            { f = s3f; out = P + 4194304;  pt = part + 65536;  blk -= 1024; }
    } else {
        C = 2048;
        if (blk < 4096) { f = t4f; out = P + 8388608;  pt = part + 131072; blk -= 2048; }
        else            { f = s4f; out = P + 16777216; pt = part + 262144; blk -= 4096; }
    }
    const int p0 = (blk & 63) * 64;
    const int c0 = (blk >> 6) * 64;
    const int cblk = blk >> 6;
    const float* src = f + ((size_t)b * C + c0) * HW + p0;
    {
        const int cl = t >> 4;
        const int pl = (t & 15) * 4;
#pragma unroll
        for (int it = 0; it < 4; ++it) {
            float4 v = *(const float4*)(src + (size_t)(cl + it * 16) * HW + pl);
            tile[cl + it * 16][pl + 0] = v.x;
            tile[cl + it * 16][pl + 1] = v.y;
            tile[cl + it * 16][pl + 2] = v.z;
            tile[cl + it * 16][pl + 3] = v.w;
        }
    }
    __syncthreads();
    const int pr = t >> 3;
    const int cb = (t & 7) * 8;
#pragma unroll
    for (int it = 0; it < 2; ++it) {
        const int p = pr + it * 32;
        union { _Float16 h[8]; float4 v4; } H;
        float ssq = 0.f;
#pragma unroll
        for (int u = 0; u < 8; ++u) {
            float v = tile[cb + u][p];
            H.h[u] = (_Float16)v;
            ssq = fmaf(v, v, ssq);
        }
        *(float4*)(out + (size_t)(p0 + p) * C + c0 + cb) = H.v4;
        // sum the 8 octet-partials (8 consecutive lanes share p)
        ssq += __shfl_down(ssq, 4);
        ssq += __shfl_down(ssq, 2);
        ssq += __shfl_down(ssq, 1);
        if ((t & 7) == 0) pt[(size_t)cblk * 4096 + p0 + p] = ssq;
    }
}

// part order: t3 | s3 | t4 | s4 ; inv order: s3 | t3 | s4 | t4 (8192 apart, [b*4096+pos])
__global__ __launch_bounds__(256) void norm_finalize_b(const float* __restrict__ part,
                                                       float* __restrict__ inv, int b) {
    const int idx = blockIdx.x * 256 + threadIdx.x;   // 0..16383
    const int tensor = idx >> 12;
    const int pos = idx & 4095;
    const int nblk[4] = {16, 16, 32, 32};
    const int poff[4] = {0, 65536, 131072, 262144};
    const int ivoff[4] = {8192, 0, 24576, 16384};
    const float* pt = part + poff[tensor] + pos;
    float s = 0.f;
    const int n = nblk[tensor];
    for (int k = 0; k < n; ++k) s += pt[(size_t)k * 4096];
    inv[ivoff[tensor] + b * 4096 + pos] = 1.0f / sqrtf(s + 1e-6f);
}

// ---------------- fused dual-level fp16 MFMA correlation GEMM, per batch ----------------
// M[b,j,i] = relu(dot3*n3) * relu(dot4*n4)  (fp16), MT[b,i,j] = M[b,j,i]
// 2-phase double-buffered LDS: K-tile t+1 staged while tile t computes; one barrier/K-step.
__global__ __launch_bounds__(256, 2) void corr_fused(
    const _Float16* __restrict__ A3, const _Float16* __restrict__ B3,
    const _Float16* __restrict__ A4, const _Float16* __restrict__ B4,
    const float* __restrict__ invA3, const float* __restrict__ invB3,
    const float* __restrict__ invA4, const float* __restrict__ invB4,
    _Float16* __restrict__ M, _Float16* __restrict__ MT, int b) {
    __shared__ char lds[65536];   // 2 x (A tile 128x64 fp16 16KB | B tile 16KB)
    const int tid = threadIdx.x;
    const int i0 = blockIdx.x * 128;
    const int j0 = blockIdx.y * 128;
    const int lane = tid & 63;
    const int w = tid >> 6;
    const int wj = (w >> 1) * 64, wi = (w & 1) * 64;
    const int quad = lane >> 4;

    // fragment LDS offsets; row stride 128 B (8 chunks of 16 B), chunk swizzle ^(row&7)
    int offA[2][4], offB[2][4];
#pragma unroll
    for (int f = 0; f < 4; ++f) {
        int jr = wj + f * 16 + (lane & 15);
        int baseA = jr * 128 + ((quad ^ (jr & 3)) << 4);
        int xkA = ((jr >> 2) & 1) << 6;
        offA[0][f] = baseA + xkA;
        offA[1][f] = baseA + (64 ^ xkA);
        int ir = wi + f * 16 + (lane & 15);
        int baseB = 16384 + ir * 128 + ((quad ^ (ir & 3)) << 4);
        int xkB = ((ir >> 2) & 1) << 6;
        offB[0][f] = baseB + xkB;
        offB[1][f] = baseB + (64 ^ xkB);
    }

    // staging slot geometry: slot g = s*256+tid; row = (g>>3)&127, chunk = g&7,
    // global chunk = chunk ^ (row&7); issues 0-3 = A tile, 4-7 = B tile
    int srow[8], selem[8];
#pragma unroll
    for (int s = 0; s < 8; ++s) {
        int g = s * 256 + tid;
        srow[s] = (g >> 3) & 127;
        selem[s] = ((g & 7) ^ (srow[s] & 7)) << 3;
    }

    const _Float16* s3p[8];
    const _Float16* s4p[8];
#pragma unroll
    for (int s = 0; s < 8; ++s) {
        if (s < 4) {
            s3p[s] = A3 + (size_t)(j0 + srow[s]) * 1024 + selem[s];
            s4p[s] = A4 + (size_t)(j0 + srow[s]) * 2048 + selem[s];
        } else {
            s3p[s] = B3 + (size_t)(i0 + srow[s]) * 1024 + selem[s];
            s4p[s] = B4 + (size_t)(i0 + srow[s]) * 2048 + selem[s];
        }
    }

    half4_t v3p[4][4];
    f32x4 acc[4][4] = {};

    auto stage = [&](int buf, const _Float16** sp) {
#pragma unroll
        for (int s = 0; s < 8; ++s) {
            __builtin_amdgcn_global_load_lds(
                (const __attribute__((address_space(1))) void*)(sp[s]),
                (__attribute__((address_space(3))) void*)(lds + (buf << 15) +
                                                          (s * 256 + tid) * 16),
                16, 0, 0);
            sp[s] += 64;
        }
    };
    auto compute = [&](int buf) {
        const int bo = buf << 15;
#pragma unroll
        for (int st = 0; st < 2; ++st) {
            half8_t a[4], bb[4];
#pragma unroll
            for (int f = 0; f < 4; ++f) {
                a[f] = *(const half8_t*)(lds + bo + offA[st][f]);
                bb[f] = *(const half8_t*)(lds + bo + offB[st][f]);
            }
#pragma unroll
            for (int fy = 0; fy < 4; ++fy)
#pragma unroll
                for (int fx = 0; fx < 4; ++fx)
                    acc[fy][fx] = __builtin_amdgcn_mfma_f32_16x16x32_f16(
                        a[fy], bb[fx], acc[fy][fx], 0, 0, 0);
        }
    };

    // prologue: stage level-3 tile 0
    stage(0, s3p);
    __syncthreads();
    int cur = 0;
#pragma unroll 1
    for (int kt = 0; kt < 16; ++kt) {
        if (kt < 15) stage(cur ^ 1, s3p);
        else         stage(cur ^ 1, s4p);    // cross-phase prefetch: level-4 tile 0
        compute(cur);
        __syncthreads();                     // drains prefetch (vmcnt0) + lds reads
        cur ^= 1;
    }

    // ph0 epilogue: stash relu(corr3) as fp16, reset acc (registers only)
    {
        const int ib = i0 + wi + (lane & 15);
        float sB[4];
#pragma unroll
        for (int fx = 0; fx < 4; ++fx) sB[fx] = invB3[b * 4096 + ib + fx * 16];
#pragma unroll
        for (int fy = 0; fy < 4; ++fy) {
            const int jb = j0 + wj + fy * 16 + quad * 4;
            float sA[4];
#pragma unroll
            for (int r = 0; r < 4; ++r) sA[r] = invA3[b * 4096 + jb + r];
#pragma unroll
            for (int fx = 0; fx < 4; ++fx)
#pragma unroll
                for (int r = 0; r < 4; ++r) {
                    v3p[fy][fx][r] =
                        (_Float16)fmaxf(acc[fy][fx][r] * sA[r] * sB[fx], 0.f);
                    acc[fy][fx][r] = 0.f;
                }
        }
    }

#pragma unroll 1
    for (int kt = 0; kt < 32; ++kt) {
        if (kt < 31) stage(cur ^ 1, s4p);
        compute(cur);
        __syncthreads();
        cur ^= 1;
    }

    // final epilogue: level4 relu x stashed level3; C/D layout col(i)=lane&15, row(j)=quad*4+r
    const int ib = i0 + wi + (lane & 15);
    float sB[4];
#pragma unroll
    for (int fx = 0; fx < 4; ++fx) sB[fx] = invB4[b * 4096 + ib + fx * 16];
#pragma unroll
    for (int fy = 0; fy < 4; ++fy) {
        const int jb = j0 + wj + fy * 16 + quad * 4;
        float sA[4];
#pragma unroll
        for (int r = 0; r < 4; ++r) sA[r] = invA4[b * 4096 + jb + r];
#pragma unroll
        for (int fx = 0; fx < 4; ++fx) {
            const int ii = ib + fx * 16;
            union { _Float16 h[4]; double d; } pk;
#pragma unroll
            for (int r = 0; r < 4; ++r) {
                float v = fmaxf(acc[fy][fx][r] * sA[r] * sB[fx], 0.f) *
                          (float)v3p[fy][fx][r];
                M[((size_t)b * HW + (jb + r)) * HW + ii] = (_Float16)v;
                pk.h[r] = (_Float16)v;
            }
            *(double*)(MT + ((size_t)b * HW + ii) * HW + jb) = pk.d;
        }
    }
}

// exact top-2 merge under total order (value desc, index asc) — order-independent
__device__ __forceinline__ void top2_merge(float& a1, int& ai1, float& a2, int& ai2,
                                           float b1, int bi1, float b2, int bi2) {
    float n1, n2;
    int ni1, ni2;
    bool bfirst = (b1 > a1) || (b1 == a1 && bi1 < ai1);
    if (bfirst) {
        n1 = b1; ni1 = bi1;
        if (a1 > b2 || (a1 == b2 && ai1 < bi2)) { n2 = a1; ni2 = ai1; }
        else { n2 = b2; ni2 = bi2; }
    } else {
        n1 = a1; ni1 = ai1;
        if (b1 > a2 || (b1 == a2 && bi1 < ai2)) { n2 = b1; ni2 = bi1; }
        else { n2 = a2; ni2 = ai2; }
    }
    a1 = n1; ai1 = ni1; a2 = n2; ai2 = ni2;
}

// ---------------- fused per-line soft-argmax, TWO lines per block ----------------
// 256 threads; both rows' loads issued up front (2x MLP); rows kept in registers
// through pass1/pass2; fixup line-features in registers (no lf LDS); butterflies
// process both lines per shuffle round; 3 barriers on the common path for 2 lines.
__global__ __launch_bounds__(256, 6) void soft_argmax(
    const _Float16* __restrict__ M, const _Float16* __restrict__ MT,
    float* __restrict__ out,
    const float* __restrict__ s3, const float* __restrict__ t3,
    const float* __restrict__ s4, const float* __restrict__ t4,
    const float* __restrict__ inv) {
    __shared__ _Float16 bufh[2][HW];   // 16 KB: fixup candidate scan only
    __shared__ float gtab[2][128];
    __shared__ float wsA[2][4], wsB[2][4], wsC[2][4];
    __shared__ int wiA[2][4], wiB[2][4];
    __shared__ int cnd[64];
    __shared__ int ncnd;
    __shared__ float bestE;
    __shared__ int bestI;
    const int tid = threadIdx.x;
    const int lane = tid & 63;
    const int wv = tid >> 6;
    const int b = blockIdx.y;
    const int line0 = blockIdx.x * 2;
    const int colmode = blockIdx.z;

    // role selection: colmode=1 (s2t): lines i, candidates j (tgt features)
    const float* cf3 = colmode ? t3 : s3;
    const float* lf3 = colmode ? s3 : t3;
    const float* cf4 = colmode ? t4 : s4;
    const float* lf4 = colmode ? s4 : t4;
    const float* invc3 = inv + (colmode ? 8192 : 0);
    const float* invl3 = inv + (colmode ? 0 : 8192);
    const float* invc4 = inv + (colmode ? 24576 : 16384);
    const float* invl4 = inv + (colmode ? 16384 : 24576);

    const _Float16* srcbase = (colmode ? MT : M) + ((size_t)b * HW + line0) * HW;

    // ---- issue both rows' loads up front; keep in registers ----
    half8_t h[2][2];
#pragma unroll
    for (int l = 0; l < 2; ++l) {
        const half8_t* s8 = (const half8_t*)(srcbase + (size_t)l * HW);
#pragma unroll
        for (int it = 0; it < 2; ++it) h[l][it] = s8[tid + it * 256];
    }
#pragma unroll
    for (int l = 0; l < 2; ++l)
#pragma unroll
        for (int it = 0; it < 2; ++it)
            *(half8_t*)(&bufh[l][(tid + it * 256) * 8]) = h[l][it];

    // ---- pass 1: sumsq + top-2 (value desc, index asc) per line, from registers ----
    float ss[2] = {0.f, 0.f}, v1[2] = {-1.f, -1.f}, v2[2] = {-1.f, -1.f};
    int i1[2] = {0, 0}, i2[2] = {0, 0};
#pragma unroll
    for (int l = 0; l < 2; ++l)
#pragma unroll
        for (int it = 0; it < 2; ++it)
#pragma unroll
            for (int u = 0; u < 8; ++u) {
                float v = (float)h[l][it][u];
                int j = (tid + it * 256) * 8 + u;
                ss[l] = fmaf(v, v, ss[l]);
                if (v > v1[l]) { v2[l] = v1[l]; i2[l] = i1[l]; v1[l] = v; i1[l] = j; }
                else if (v > v2[l]) { v2[l] = v; i2[l] = j; }
            }
#pragma unroll
    for (int m = 1; m < 64; m <<= 1)
#pragma unroll
        for (int l = 0; l < 2; ++l) {
            ss[l] += __shfl_xor(ss[l], m);
            float b1 = __shfl_xor(v1[l], m); int bi1 = __shfl_xor(i1[l], m);
            float b2 = __shfl_xor(v2[l], m); int bi2 = __shfl_xor(i2[l], m);
            top2_merge(v1[l], i1[l], v2[l], i2[l], b1, bi1, b2, bi2);
        }
    if (lane == 0)
#pragma unroll
        for (int l = 0; l < 2; ++l) {
            wsA[l][wv] = ss[l]; wsB[l][wv] = v1[l]; wiA[l][wv] = i1[l];
            wsC[l][wv] = v2[l]; wiB[l][wv] = i2[l];
        }
    __syncthreads();   // also covers bufh row-buffer writes

    // all threads merge the 4 wave partials in fixed order (identical result everywhere)
    float inv_l[2], vmax[2], m1a[2], m2a[2];
    int amax[2];
#pragma unroll
    for (int l = 0; l < 2; ++l) {
        float ssq = wsA[l][0] + wsA[l][1] + wsA[l][2] + wsA[l][3];
        float m1 = wsB[l][0], m2 = wsC[l][0];
        int mi1 = wiA[l][0], mi2 = wiB[l][0];
#pragma unroll
        for (int k = 1; k < 4; ++k)
            top2_merge(m1, mi1, m2, mi2, wsB[l][k], wiA[l][k], wsC[l][k], wiB[l][k]);
        inv_l[l] = 1.0f / sqrtf(ssq + 1e-6f);
        vmax[l] = m1 * inv_l[l];
        amax[l] = mi1;
        m1a[l] = m1; m2a[l] = m2;
        (void)mi2;
    }

    // near-tie fixup per line (block-uniform branch): exact fp32 recompute of every
    // candidate within threshold; line features live in 12 registers (same c-order).
#pragma unroll
    for (int l = 0; l < 2; ++l) {
        const float m1 = m1a[l], m2 = m2a[l];
        const float cut = m1 - FIXUP_THR * m1;
        if (m2 >= cut) {
            const int line = line0 + l;
            if (tid == 0) { ncnd = 0; bestE = -1.f; bestI = 1 << 30; }
            __syncthreads();
            for (int j = tid; j < HW; j += 256)
                if ((float)bufh[l][j] >= cut) {
                    int k = atomicAdd(&ncnd, 1);
                    if (k < 64) cnd[k] = j;
                }
            float lf3r[4], lf4r[8];
#pragma unroll
            for (int q = 0; q < 4; ++q)
                lf3r[q] = lf3[((size_t)b * 1024 + tid + q * 256) * HW + line];
#pragma unroll
            for (int q = 0; q < 8; ++q)
                lf4r[q] = lf4[((size_t)b * 2048 + tid + q * 256) * HW + line];
            __syncthreads();
            int nc = ncnd < 64 ? ncnd : 64;
#pragma unroll 1
            for (int k = 0; k < nc; ++k) {
                int jc = cnd[k];
                float d3 = 0.f, d4 = 0.f;
#pragma unroll
                for (int q = 0; q < 4; ++q)
                    d3 = fmaf(cf3[((size_t)b * 1024 + tid + q * 256) * HW + jc],
                              lf3r[q], d3);
#pragma unroll
                for (int q = 0; q < 8; ++q)
                    d4 = fmaf(cf4[((size_t)b * 2048 + tid + q * 256) * HW + jc],
                              lf4r[q], d4);
#pragma unroll
                for (int m = 1; m < 64; m <<= 1) {
                    d3 += __shfl_xor(d3, m);
                    d4 += __shfl_xor(d4, m);
                }
                if (lane == 0) { wsA[0][wv] = d3; wsB[0][wv] = d4; }
                __syncthreads();
                if (tid == 0) {
                    float s3d = wsA[0][0] + wsA[0][1] + wsA[0][2] + wsA[0][3];
                    float s4d = wsB[0][0] + wsB[0][1] + wsB[0][2] + wsB[0][3];
                    float e3 = fmaxf(s3d * invc3[b * 4096 + jc] *
                                     invl3[b * 4096 + line], 0.f);
                    float e4 = fmaxf(s4d * invc4[b * 4096 + jc] *
                                     invl4[b * 4096 + line], 0.f);
                    float e = e3 * e4;
                    if (e > bestE || (e == bestE && jc < bestI)) { bestE = e; bestI = jc; }
                }
                __syncthreads();
            }
            amax[l] = bestI;
        }
    }

    // separable gaussian tables for both lines: 256 threads cover 2 x 128 entries
    const float ax0 = (float)(amax[0] & 63), ay0 = (float)(amax[0] >> 6);
    const float ax1 = (float)(amax[1] & 63), ay1 = (float)(amax[1] >> 6);
    {
        const int gl = tid >> 7;
        const int idx = tid & 127;
        const float axv = gl ? ax1 : ax0;
        const float ayv = gl ? ay1 : ay0;
        float d = (float)(idx & 63) - ((idx < 64) ? axv : ayv);
        gtab[gl][idx] = __expf(-d * d * 0.02f);
    }
    __syncthreads();   // separates pass-1 ws reads from pass-2 ws writes too

    // pass 2: gaussian-masked softmax expectation per line, from registers
    float se[2], sx[2], sy[2];
#pragma unroll
    for (int l = 0; l < 2; ++l) {
        float seL = 0.f, sxL = 0.f, syL = 0.f;
#pragma unroll
        for (int it = 0; it < 2; ++it) {
            const int j8 = tid + it * 256;
            const int x0 = (j8 & 7) * 8;
            const int y2 = j8 >> 3;
            const float gyi = gtab[l][64 + y2] * inv_l[l];
            const float yn = fmaf((float)y2, 2.0f / 63.0f, -1.0f);
            float sec = 0.f;
#pragma unroll
            for (int u = 0; u < 8; ++u) {
                float v = gtab[l][x0 + u] * (float)h[l][it][u] * gyi;
                float e = __expf(50.0f * (v - vmax[l]));      // beta = 50
                sec += e;
                sxL = fmaf(e, fmaf((float)(x0 + u), 2.0f / 63.0f, -1.0f), sxL);
            }
            seL += sec;
            syL = fmaf(sec, yn, syL);
        }
        se[l] = seL; sx[l] = sxL; sy[l] = syL;
    }
#pragma unroll
    for (int m = 1; m < 64; m <<= 1)
#pragma unroll
        for (int l = 0; l < 2; ++l) {
            se[l] += __shfl_xor(se[l], m);
            sx[l] += __shfl_xor(sx[l], m);
            sy[l] += __shfl_xor(sy[l], m);
        }
    if (lane == 0)
#pragma unroll
        for (int l = 0; l < 2; ++l) {
            wsA[l][wv] = se[l]; wsB[l][wv] = sx[l]; wsC[l][wv] = sy[l];
        }
    __syncthreads();
    if (tid == 0) {
#pragma unroll
        for (int l = 0; l < 2; ++l) {
            float S = wsA[l][0] + wsA[l][1] + wsA[l][2] + wsA[l][3];
            float X = wsB[l][0] + wsB[l][1] + wsB[l][2] + wsB[l][3];
            float Y = wsC[l][0] + wsC[l][1] + wsC[l][2] + wsC[l][3];
            float gx = X / S;
            float gy = Y / S;
            const int line = line0 + l;
            size_t gbase = colmode ? 0 : 32768;
            size_t fbase = colmode ? 16384 : 49152;
            size_t p = gbase + ((size_t)b * HW + line) * 2;
            out[p] = gx;
            out[p + 1] = gy;
            out[fbase + (size_t)(b * 2 + 0) * HW + line] = 0.f;
            out[fbase + (size_t)(b * 2 + 1) * HW + line] = 0.f;
        }
    }
}

extern "C" void kernel_launch(void* const* d_in, const int* in_sizes, int n_in,
                              void* d_out, int out_size, void* d_ws, size_t ws_size,
                              hipStream_t stream) {
    const float* s3 = (const float*)d_in[0];
    const float* t3 = (const float*)d_in[1];
    const float* s4 = (const float*)d_in[2];
    const float* t4 = (const float*)d_in[3];
    float* out = (float*)d_out;
    char* base = (char*)d_ws;

    // ws layout (bytes):
    //   inv    [0, 131072)                    4 tensors x [b][4096] fp32
    //   part   [131072, 1703936)              norm partials (t3|s3|t4|s4)
    //   M16    [1703936, 68812800)            fp16 2x4096x4096
    //   MT16   [68812800, 135921664)          fp16 transpose
    //   planes [135921664, 186253312)         per-batch fp16: t3|s3|t4|s4
    // total 186.3 MB (< 201.4 MB proven available)
    float* inv = (float*)base;
    float* part = (float*)(base + 131072);
    _Float16* M16 = (_Float16*)(base + 1703936);
    _Float16* MT16 = (_Float16*)(base + 68812800);
    _Float16* P = (_Float16*)(base + 135921664);

    dim3 gg(32, 32);
    for (int b = 0; b < 2; ++b) {
        transpose_b<<<6144, 256, 0, stream>>>(s3, t3, s4, t4, P, part, b);
        norm_finalize_b<<<64, 256, 0, stream>>>(part, inv, b);
        corr_fused<<<gg, 256, 0, stream>>>(P, P + 4194304, P + 8388608, P + 16777216,
                                           inv + 8192, inv + 0, inv + 24576, inv + 16384,
                                           M16, MT16, b);
    }

    dim3 rg(2048, 2, 2);
    soft_argmax<<<rg, 256, 0, stream>>>(M16, MT16, out, s3, t3, s4, t4, inv);
}

// Round 7
// 571.777 us; speedup vs baseline: 1.2380x; 1.2380x over previous
//
#include <hip/hip_runtime.h>
#include <math.h>

#define HW 4096
#define FIXUP_THR 4e-3f

typedef _Float16 half8_t __attribute__((ext_vector_type(8)));
typedef _Float16 half4_t __attribute__((ext_vector_type(4)));
typedef float f32x4 __attribute__((ext_vector_type(4)));

// ------- merged per-batch transpose to fp16 + per-position sumsq partials -------
// one dispatch covers all 4 tensors of batch b: blk [0,1024)=t3, [1024,2048)=s3,
// [2048,4096)=t4, [4096,6144)=s4. f[b][c][pos] -> out[pos][c]; part = per-cblk sumsq.
__global__ __launch_bounds__(256) void transpose_b(
    const float* __restrict__ s3f, const float* __restrict__ t3f,
    const float* __restrict__ s4f, const float* __restrict__ t4f,
    _Float16* __restrict__ P, float* __restrict__ part, int b) {
    __shared__ float tile[64][65];
    const int t = threadIdx.x;
    int blk = blockIdx.x;
    const float* f;
    _Float16* out;
    float* pt;
    int C;
    if (blk < 2048) {
        C = 1024;
        if (blk < 1024) { f = t3f; out = P;            pt = part;          }
        else            { f = s3f; out = P + 4194304;  pt = part + 65536;  blk -= 1024; }
    } else {
        C = 2048;
        if (blk < 4096) { f = t4f; out = P + 8388608;  pt = part + 131072; blk -= 2048; }
        else            { f = s4f; out = P + 16777216; pt = part + 262144; blk -= 4096; }
    }
    const int p0 = (blk & 63) * 64;
    const int c0 = (blk >> 6) * 64;
    const int cblk = blk >> 6;
    const float* src = f + ((size_t)b * C + c0) * HW + p0;
    {
        const int cl = t >> 4;
        const int pl = (t & 15) * 4;
#pragma unroll
        for (int it = 0; it < 4; ++it) {
            float4 v = *(const float4*)(src + (size_t)(cl + it * 16) * HW + pl);
            tile[cl + it * 16][pl + 0] = v.x;
            tile[cl + it * 16][pl + 1] = v.y;
            tile[cl + it * 16][pl + 2] = v.z;
            tile[cl + it * 16][pl + 3] = v.w;
        }
    }
    __syncthreads();
    const int pr = t >> 3;
    const int cb = (t & 7) * 8;
#pragma unroll
    for (int it = 0; it < 2; ++it) {
        const int p = pr + it * 32;
        union { _Float16 h[8]; float4 v4; } H;
        float ssq = 0.f;
#pragma unroll
        for (int u = 0; u < 8; ++u) {
            float v = tile[cb + u][p];
            H.h[u] = (_Float16)v;
            ssq = fmaf(v, v, ssq);
        }
        *(float4*)(out + (size_t)(p0 + p) * C + c0 + cb) = H.v4;
        // sum the 8 octet-partials (8 consecutive lanes share p)
        ssq += __shfl_down(ssq, 4);
        ssq += __shfl_down(ssq, 2);
        ssq += __shfl_down(ssq, 1);
        if ((t & 7) == 0) pt[(size_t)cblk * 4096 + p0 + p] = ssq;
    }
}

// part order: t3 | s3 | t4 | s4 ; inv order: s3 | t3 | s4 | t4 (8192 apart, [b*4096+pos])
__global__ __launch_bounds__(256) void norm_finalize_b(const float* __restrict__ part,
                                                       float* __restrict__ inv, int b) {
    const int idx = blockIdx.x * 256 + threadIdx.x;   // 0..16383
    const int tensor = idx >> 12;
    const int pos = idx & 4095;
    const int nblk[4] = {16, 16, 32, 32};
    const int poff[4] = {0, 65536, 131072, 262144};
    const int ivoff[4] = {8192, 0, 24576, 16384};
    const float* pt = part + poff[tensor] + pos;
    float s = 0.f;
    const int n = nblk[tensor];
    for (int k = 0; k < n; ++k) s += pt[(size_t)k * 4096];
    inv[ivoff[tensor] + b * 4096 + pos] = 1.0f / sqrtf(s + 1e-6f);
}

// ---------------- fused dual-level fp16 MFMA correlation GEMM, per batch ----------------
// M[b,j,i] = relu(dot3*n3) * relu(dot4*n4)  (fp16), MT[b,i,j] = M[b,j,i]
// 2-phase double-buffered LDS: K-tile t+1 staged while tile t computes; one barrier/K-step.
__global__ __launch_bounds__(256, 2) void corr_fused(
    const _Float16* __restrict__ A3, const _Float16* __restrict__ B3,
    const _Float16* __restrict__ A4, const _Float16* __restrict__ B4,
    const float* __restrict__ invA3, const float* __restrict__ invB3,
    const float* __restrict__ invA4, const float* __restrict__ invB4,
    _Float16* __restrict__ M, _Float16* __restrict__ MT, int b) {
    __shared__ char lds[65536];   // 2 x (A tile 128x64 fp16 16KB | B tile 16KB)
    const int tid = threadIdx.x;
    const int i0 = blockIdx.x * 128;
    const int j0 = blockIdx.y * 128;
    const int lane = tid & 63;
    const int w = tid >> 6;
    const int wj = (w >> 1) * 64, wi = (w & 1) * 64;
    const int quad = lane >> 4;

    // fragment LDS offsets; row stride 128 B (8 chunks of 16 B), chunk swizzle ^(row&7)
    int offA[2][4], offB[2][4];
#pragma unroll
    for (int f = 0; f < 4; ++f) {
        int jr = wj + f * 16 + (lane & 15);
        int baseA = jr * 128 + ((quad ^ (jr & 3)) << 4);
        int xkA = ((jr >> 2) & 1) << 6;
        offA[0][f] = baseA + xkA;
        offA[1][f] = baseA + (64 ^ xkA);
        int ir = wi + f * 16 + (lane & 15);
        int baseB = 16384 + ir * 128 + ((quad ^ (ir & 3)) << 4);
        int xkB = ((ir >> 2) & 1) << 6;
        offB[0][f] = baseB + xkB;
        offB[1][f] = baseB + (64 ^ xkB);
    }

    // staging slot geometry: slot g = s*256+tid; row = (g>>3)&127, chunk = g&7,
    // global chunk = chunk ^ (row&7); issues 0-3 = A tile, 4-7 = B tile
    int srow[8], selem[8];
#pragma unroll
    for (int s = 0; s < 8; ++s) {
        int g = s * 256 + tid;
        srow[s] = (g >> 3) & 127;
        selem[s] = ((g & 7) ^ (srow[s] & 7)) << 3;
    }

    const _Float16* s3p[8];
    const _Float16* s4p[8];
#pragma unroll
    for (int s = 0; s < 8; ++s) {
        if (s < 4) {
            s3p[s] = A3 + (size_t)(j0 + srow[s]) * 1024 + selem[s];
            s4p[s] = A4 + (size_t)(j0 + srow[s]) * 2048 + selem[s];
        } else {
            s3p[s] = B3 + (size_t)(i0 + srow[s]) * 1024 + selem[s];
            s4p[s] = B4 + (size_t)(i0 + srow[s]) * 2048 + selem[s];
        }
    }

    half4_t v3p[4][4];
    f32x4 acc[4][4] = {};

    auto stage = [&](int buf, const _Float16** sp) {
#pragma unroll
        for (int s = 0; s < 8; ++s) {
            __builtin_amdgcn_global_load_lds(
                (const __attribute__((address_space(1))) void*)(sp[s]),
                (__attribute__((address_space(3))) void*)(lds + (buf << 15) +
                                                          (s * 256 + tid) * 16),
                16, 0, 0);
            sp[s] += 64;
        }
    };
    auto compute = [&](int buf) {
        const int bo = buf << 15;
#pragma unroll
        for (int st = 0; st < 2; ++st) {
            half8_t a[4], bb[4];
#pragma unroll
            for (int f = 0; f < 4; ++f) {
                a[f] = *(const half8_t*)(lds + bo + offA[st][f]);
                bb[f] = *(const half8_t*)(lds + bo + offB[st][f]);
            }
#pragma unroll
            for (int fy = 0; fy < 4; ++fy)
#pragma unroll
                for (int fx = 0; fx < 4; ++fx)
                    acc[fy][fx] = __builtin_amdgcn_mfma_f32_16x16x32_f16(
                        a[fy], bb[fx], acc[fy][fx], 0, 0, 0);
        }
    };

    // prologue: stage level-3 tile 0
    stage(0, s3p);
    __syncthreads();
    int cur = 0;
#pragma unroll 1
    for (int kt = 0; kt < 16; ++kt) {
        if (kt < 15) stage(cur ^ 1, s3p);
        else         stage(cur ^ 1, s4p);    // cross-phase prefetch: level-4 tile 0
        compute(cur);
        __syncthreads();                     // drains prefetch (vmcnt0) + lds reads
        cur ^= 1;
    }

    // ph0 epilogue: stash relu(corr3) as fp16, reset acc (registers only)
    {
        const int ib = i0 + wi + (lane & 15);
        float sB[4];
#pragma unroll
        for (int fx = 0; fx < 4; ++fx) sB[fx] = invB3[b * 4096 + ib + fx * 16];
#pragma unroll
        for (int fy = 0; fy < 4; ++fy) {
            const int jb = j0 + wj + fy * 16 + quad * 4;
            float sA[4];
#pragma unroll
            for (int r = 0; r < 4; ++r) sA[r] = invA3[b * 4096 + jb + r];
#pragma unroll
            for (int fx = 0; fx < 4; ++fx)
#pragma unroll
                for (int r = 0; r < 4; ++r) {
                    v3p[fy][fx][r] =
                        (_Float16)fmaxf(acc[fy][fx][r] * sA[r] * sB[fx], 0.f);
                    acc[fy][fx][r] = 0.f;
                }
        }
    }

#pragma unroll 1
    for (int kt = 0; kt < 32; ++kt) {
        if (kt < 31) stage(cur ^ 1, s4p);
        compute(cur);
        __syncthreads();
        cur ^= 1;
    }

    // final epilogue: level4 relu x stashed level3; C/D layout col(i)=lane&15, row(j)=quad*4+r
    const int ib = i0 + wi + (lane & 15);
    float sB[4];
#pragma unroll
    for (int fx = 0; fx < 4; ++fx) sB[fx] = invB4[b * 4096 + ib + fx * 16];
#pragma unroll
    for (int fy = 0; fy < 4; ++fy) {
        const int jb = j0 + wj + fy * 16 + quad * 4;
        float sA[4];
#pragma unroll
        for (int r = 0; r < 4; ++r) sA[r] = invA4[b * 4096 + jb + r];
#pragma unroll
        for (int fx = 0; fx < 4; ++fx) {
            const int ii = ib + fx * 16;
            union { _Float16 h[4]; double d; } pk;
#pragma unroll
            for (int r = 0; r < 4; ++r) {
                float v = fmaxf(acc[fy][fx][r] * sA[r] * sB[fx], 0.f) *
                          (float)v3p[fy][fx][r];
                M[((size_t)b * HW + (jb + r)) * HW + ii] = (_Float16)v;
                pk.h[r] = (_Float16)v;
            }
            *(double*)(MT + ((size_t)b * HW + ii) * HW + jb) = pk.d;
        }
    }
}

// exact top-2 merge under total order (value desc, index asc) — order-independent
__device__ __forceinline__ void top2_merge(float& a1, int& ai1, float& a2, int& ai2,
                                           float b1, int bi1, float b2, int bi2) {
    float n1, n2;
    int ni1, ni2;
    bool bfirst = (b1 > a1) || (b1 == a1 && bi1 < ai1);
    if (bfirst) {
        n1 = b1; ni1 = bi1;
        if (a1 > b2 || (a1 == b2 && ai1 < bi2)) { n2 = a1; ni2 = ai1; }
        else { n2 = b2; ni2 = bi2; }
    } else {
        n1 = a1; ni1 = ai1;
        if (b1 > a2 || (b1 == a2 && bi1 < ai2)) { n2 = b1; ni2 = bi1; }
        else { n2 = a2; ni2 = ai2; }
    }
    a1 = n1; ai1 = ni1; a2 = n2; ai2 = ni2;
}

// ---------------- fused per-line soft-argmax, TWO lines per block ----------------
// 256 threads; rows register-resident (4 x half8/thread); fixup candidate scan from
// registers (no LDS row buffer); fixup line-features staged in LDS (R3-proven path);
// launch_bounds(256,4) gives 128-VGPR budget -> no scratch spill.
__global__ __launch_bounds__(256, 4) void soft_argmax(
    const _Float16* __restrict__ M, const _Float16* __restrict__ MT,
    float* __restrict__ out,
    const float* __restrict__ s3, const float* __restrict__ t3,
    const float* __restrict__ s4, const float* __restrict__ t4,
    const float* __restrict__ inv) {
    __shared__ float lf[3072];        // fixup-only line features (12 KB)
    __shared__ float gtab[2][128];
    __shared__ float wsA[2][4], wsB[2][4], wsC[2][4];
    __shared__ int wiA[2][4], wiB[2][4];
    __shared__ int cnd[64];
    __shared__ int ncnd;
    __shared__ float bestE;
    __shared__ int bestI;
    const int tid = threadIdx.x;
    const int lane = tid & 63;
    const int wv = tid >> 6;
    const int b = blockIdx.y;
    const int line0 = blockIdx.x * 2;
    const int colmode = blockIdx.z;

    // role selection: colmode=1 (s2t): lines i, candidates j (tgt features)
    const float* cf3 = colmode ? t3 : s3;
    const float* lf3 = colmode ? s3 : t3;
    const float* cf4 = colmode ? t4 : s4;
    const float* lf4 = colmode ? s4 : t4;
    const float* invc3 = inv + (colmode ? 8192 : 0);
    const float* invl3 = inv + (colmode ? 0 : 8192);
    const float* invc4 = inv + (colmode ? 24576 : 16384);
    const float* invl4 = inv + (colmode ? 16384 : 24576);

    const _Float16* srcbase = (colmode ? MT : M) + ((size_t)b * HW + line0) * HW;

    // ---- issue both rows' loads up front; keep in registers ----
    half8_t h[2][2];
#pragma unroll
    for (int l = 0; l < 2; ++l) {
        const half8_t* s8 = (const half8_t*)(srcbase + (size_t)l * HW);
#pragma unroll
        for (int it = 0; it < 2; ++it) h[l][it] = s8[tid + it * 256];
    }

    // ---- pass 1: sumsq + top-2 (value desc, index asc) per line, from registers ----
    float ss[2] = {0.f, 0.f}, v1[2] = {-1.f, -1.f}, v2[2] = {-1.f, -1.f};
    int i1[2] = {0, 0}, i2[2] = {0, 0};
#pragma unroll
    for (int l = 0; l < 2; ++l)
#pragma unroll
        for (int it = 0; it < 2; ++it)
#pragma unroll
            for (int u = 0; u < 8; ++u) {
                float v = (float)h[l][it][u];
                int j = (tid + it * 256) * 8 + u;
                ss[l] = fmaf(v, v, ss[l]);
                if (v > v1[l]) { v2[l] = v1[l]; i2[l] = i1[l]; v1[l] = v; i1[l] = j; }
                else if (v > v2[l]) { v2[l] = v; i2[l] = j; }
            }
#pragma unroll
    for (int m = 1; m < 64; m <<= 1)
#pragma unroll
        for (int l = 0; l < 2; ++l) {
            ss[l] += __shfl_xor(ss[l], m);
            float b1 = __shfl_xor(v1[l], m); int bi1 = __shfl_xor(i1[l], m);
            float b2 = __shfl_xor(v2[l], m); int bi2 = __shfl_xor(i2[l], m);
            top2_merge(v1[l], i1[l], v2[l], i2[l], b1, bi1, b2, bi2);
        }
    if (lane == 0)
#pragma unroll
        for (int l = 0; l < 2; ++l) {
            wsA[l][wv] = ss[l]; wsB[l][wv] = v1[l]; wiA[l][wv] = i1[l];
            wsC[l][wv] = v2[l]; wiB[l][wv] = i2[l];
        }
    __syncthreads();

    // all threads merge the 4 wave partials in fixed order (identical result everywhere)
    float inv_l[2], vmax[2], m1a[2], m2a[2];
    int amax[2];
#pragma unroll
    for (int l = 0; l < 2; ++l) {
        float ssq = wsA[l][0] + wsA[l][1] + wsA[l][2] + wsA[l][3];
        float m1 = wsB[l][0], m2 = wsC[l][0];
        int mi1 = wiA[l][0], mi2 = wiB[l][0];
#pragma unroll
        for (int k = 1; k < 4; ++k)
            top2_merge(m1, mi1, m2, mi2, wsB[l][k], wiA[l][k], wsC[l][k], wiB[l][k]);
        inv_l[l] = 1.0f / sqrtf(ssq + 1e-6f);
        vmax[l] = m1 * inv_l[l];
        amax[l] = mi1;
        m1a[l] = m1; m2a[l] = m2;
        (void)mi2;
    }

    // near-tie fixup per line (block-uniform branch): exact fp32 recompute of every
    // candidate within threshold; candidate scan from registers, features from LDS.
#pragma unroll
    for (int l = 0; l < 2; ++l) {
        const float m1 = m1a[l], m2 = m2a[l];
        const float cut = m1 - FIXUP_THR * m1;
        if (m2 >= cut) {
            const int line = line0 + l;
            if (tid == 0) { ncnd = 0; bestE = -1.f; bestI = 1 << 30; }
            __syncthreads();
#pragma unroll
            for (int it = 0; it < 2; ++it)
#pragma unroll
                for (int u = 0; u < 8; ++u)
                    if ((float)h[l][it][u] >= cut) {
                        int k = atomicAdd(&ncnd, 1);
                        if (k < 64) cnd[k] = (tid + it * 256) * 8 + u;
                    }
            for (int c = tid; c < 1024; c += 256)
                lf[c] = lf3[((size_t)b * 1024 + c) * HW + line];
            for (int c = tid; c < 2048; c += 256)
                lf[1024 + c] = lf4[((size_t)b * 2048 + c) * HW + line];
            __syncthreads();
            int nc = ncnd < 64 ? ncnd : 64;
#pragma unroll 1
            for (int k = 0; k < nc; ++k) {
                int jc = cnd[k];
                float d3 = 0.f, d4 = 0.f;
                for (int c = tid; c < 1024; c += 256)
                    d3 = fmaf(cf3[((size_t)b * 1024 + c) * HW + jc], lf[c], d3);
                for (int c = tid; c < 2048; c += 256)
                    d4 = fmaf(cf4[((size_t)b * 2048 + c) * HW + jc], lf[1024 + c], d4);
#pragma unroll
                for (int m = 1; m < 64; m <<= 1) {
                    d3 += __shfl_xor(d3, m);
                    d4 += __shfl_xor(d4, m);
                }
                if (lane == 0) { wsA[0][wv] = d3; wsB[0][wv] = d4; }
                __syncthreads();
                if (tid == 0) {
                    float s3d = wsA[0][0] + wsA[0][1] + wsA[0][2] + wsA[0][3];
                    float s4d = wsB[0][0] + wsB[0][1] + wsB[0][2] + wsB[0][3];
                    float e3 = fmaxf(s3d * invc3[b * 4096 + jc] *
                                     invl3[b * 4096 + line], 0.f);
                    float e4 = fmaxf(s4d * invc4[b * 4096 + jc] *
                                     invl4[b * 4096 + line], 0.f);
                    float e = e3 * e4;
                    if (e > bestE || (e == bestE && jc < bestI)) { bestE = e; bestI = jc; }
                }
                __syncthreads();
            }
            amax[l] = bestI;
            __syncthreads();   // all reads of bestI complete before next line resets it
        }
    }

    // separable gaussian tables for both lines: 256 threads cover 2 x 128 entries
    const float ax0 = (float)(amax[0] & 63), ay0 = (float)(amax[0] >> 6);
    const float ax1 = (float)(amax[1] & 63), ay1 = (float)(amax[1] >> 6);
    {
        const int gl = tid >> 7;
        const int idx = tid & 127;
        const float axv = gl ? ax1 : ax0;
        const float ayv = gl ? ay1 : ay0;
        float d = (float)(idx & 63) - ((idx < 64) ? axv : ayv);
        gtab[gl][idx] = __expf(-d * d * 0.02f);
    }
    __syncthreads();   // separates pass-1 ws reads from pass-2 ws writes too

    // pass 2: gaussian-masked softmax expectation per line, from registers
    float se[2], sx[2], sy[2];
#pragma unroll
    for (int l = 0; l < 2; ++l) {
        float seL = 0.f, sxL = 0.f, syL = 0.f;
#pragma unroll
        for (int it = 0; it < 2; ++it) {
            const int j8 = tid + it * 256;
            const int x0 = (j8 & 7) * 8;
            const int y2 = j8 >> 3;
            const float gyi = gtab[l][64 + y2] * inv_l[l];
            const float yn = fmaf((float)y2, 2.0f / 63.0f, -1.0f);
            float sec = 0.f;
#pragma unroll
            for (int u = 0; u < 8; ++u) {
                float v = gtab[l][x0 + u] * (float)h[l][it][u] * gyi;
                float e = __expf(50.0f * (v - vmax[l]));      // beta = 50
                sec += e;
                sxL = fmaf(e, fmaf((float)(x0 + u), 2.0f / 63.0f, -1.0f), sxL);
            }
            seL += sec;
            syL = fmaf(sec, yn, syL);
        }
        se[l] = seL; sx[l] = sxL; sy[l] = syL;
    }
#pragma unroll
    for (int m = 1; m < 64; m <<= 1)
#pragma unroll
        for (int l = 0; l < 2; ++l) {
            se[l] += __shfl_xor(se[l], m);
            sx[l] += __shfl_xor(sx[l], m);
            sy[l] += __shfl_xor(sy[l], m);
        }
    if (lane == 0)
#pragma unroll
        for (int l = 0; l < 2; ++l) {
            wsA[l][wv] = se[l]; wsB[l][wv] = sx[l]; wsC[l][wv] = sy[l];
        }
    __syncthreads();
    if (tid == 0) {
#pragma unroll
        for (int l = 0; l < 2; ++l) {
            float S = wsA[l][0] + wsA[l][1] + wsA[l][2] + wsA[l][3];
            float X = wsB[l][0] + wsB[l][1] + wsB[l][2] + wsB[l][3];
            float Y = wsC[l][0] + wsC[l][1] + wsC[l][2] + wsC[l][3];
            float gx = X / S;
            float gy = Y / S;
            const int line = line0 + l;
            size_t gbase = colmode ? 0 : 32768;
            size_t fbase = colmode ? 16384 : 49152;
            size_t p = gbase + ((size_t)b * HW + line) * 2;
            out[p] = gx;
            out[p + 1] = gy;
            out[fbase + (size_t)(b * 2 + 0) * HW + line] = 0.f;
            out[fbase + (size_t)(b * 2 + 1) * HW + line] = 0.f;
        }
    }
}

extern "C" void kernel_launch(void* const* d_in, const int* in_sizes, int n_in,
                              void* d_out, int out_size, void* d_ws, size_t ws_size,
                              hipStream_t stream) {
    const float* s3 = (const float*)d_in[0];
    const float* t3 = (const float*)d_in[1];
    const float* s4 = (const float*)d_in[2];
    const float* t4 = (const float*)d_in[3];
    float* out = (float*)d_out;
    char* base = (char*)d_ws;

    // ws layout (bytes):
    //   inv    [0, 131072)                    4 tensors x [b][4096] fp32
    //   part   [131072, 1703936)              norm partials (t3|s3|t4|s4)
    //   M16    [1703936, 68812800)            fp16 2x4096x4096
    //   MT16   [68812800, 135921664)          fp16 transpose
    //   planes [135921664, 186253312)         per-batch fp16: t3|s3|t4|s4
    // total 186.3 MB (< 201.4 MB proven available)
    float* inv = (float*)base;
    float* part = (float*)(base + 131072);
    _Float16* M16 = (_Float16*)(base + 1703936);
    _Float16* MT16 = (_Float16*)(base + 68812800);
    _Float16* P = (_Float16*)(base + 135921664);

    dim3 gg(32, 32);
    for (int b = 0; b < 2; ++b) {
        transpose_b<<<6144, 256, 0, stream>>>(s3, t3, s4, t4, P, part, b);
        norm_finalize_b<<<64, 256, 0, stream>>>(part, inv, b);
        corr_fused<<<gg, 256, 0, stream>>>(P, P + 4194304, P + 8388608, P + 16777216,
                                           inv + 8192, inv + 0, inv + 24576, inv + 16384,
                                           M16, MT16, b);
    }

    dim3 rg(2048, 2, 2);
    soft_argmax<<<rg, 256, 0, stream>>>(M16, MT16, out, s3, t3, s4, t4, inv);
}